// Round 12
// baseline (278.528 us; speedup 1.0000x reference)
//
#include <hip/hip_runtime.h>
#include <hip/hip_bf16.h>
#include <hip/hip_fp16.h>

#define NPTS 692736      // 24*41*16*44
#define NPATCH 16896     // 24*16*44

typedef _Float16 h16;
typedef __attribute__((ext_vector_type(4))) _Float16 half4v;
typedef __attribute__((ext_vector_type(8))) _Float16 half8v;
typedef __attribute__((ext_vector_type(4))) float f32x4;

// ---------- module-scope device globals ----------
__device__ float  v11_xbuf[NPATCH*256];
__device__ float  v11_ctx[NPATCH*64];
__device__ float  v11_depth[NPATCH*41];
__device__ int    v11_ranks[NPTS];
__device__ float  v11_bev[16384*64];
__device__ double v11_geom[24*24];

// conv1 weights packed in MFMA-fragment order: [ob(4)][kt(12)][og16(4)][ks(2)][fg(4)][fr(16)][e(8)]
__device__ h16    v21_whi[196608];
__device__ h16    v21_wlo[196608];

// depth weights in fragment order: [nf(7)][ktI(8)][fg(4)][fr(16)][e(8)]  (padded o>=105 -> 0)
__device__ h16    v21_dwhi[28672];
__device__ h16    v21_dwlo[28672];

// conv2 folded weights in fragment order: [nf(4)][ktI(18)][fg(4)][fr(16)][e(8)], k = tap*64+ic
__device__ h16    v21_w2hi[36864];
__device__ h16    v21_w2lo[36864];

// counting-sort state for scatter->gather inversion
__device__ int    v12_cnt[16384];
__device__ int    v12_off[16384];
__device__ int    v12_pos[NPTS];       // position within own voxel
__device__ int2   v12_sorted[NPTS];    // (packed (p<<6)|d, rank) in rank order
__device__ int    v12_total;

__device__ __forceinline__ void inv3_v11(const double* m, double* o){
  double a=m[0],b=m[1],c=m[2],d=m[3],e=m[4],f=m[5],g=m[6],h=m[7],i=m[8];
  double A = e*i - f*h, B = -(d*i - f*g), C = d*h - e*g;
  double det = a*A + b*B + c*C;
  double id = 1.0/det;
  o[0]=A*id;            o[1]=-(b*i - c*h)*id; o[2]=(b*f - c*e)*id;
  o[3]=B*id;            o[4]=(a*i - c*g)*id;  o[5]=-(a*f - c*d)*id;
  o[6]=C*id;            o[7]=-(a*h - b*g)*id; o[8]=(a*e - b*d)*id;
}

// fused prep: zero + all three weight packs (fragment order) + geom
// grid = 4096 (zero) + 768 (conv1) + 112 (depth) + 144 (conv2) + 1 (geom) = 5121
__global__ void prep_v21(const float* cw, const float* dw, const float* enc_w,
                         const float* rots, const float* trans, const float* intrins,
                         const float* post_rots, const float* post_trans){
  int b = blockIdx.x;
  int tid = threadIdx.x;
  if (b < 4096){
    int gid = b*256 + tid;
    v11_bev[gid] = 0.f;
    if (gid < 16384) v12_cnt[gid] = 0;
  } else if (b < 4864){
    // conv1: [ob][kt][og][ks][fg][fr][e]
    int gid = (b-4096)*256 + tid;        // 0..196607
    int e  = gid & 7;
    int fr = (gid>>3) & 15;
    int fg = (gid>>7) & 3;
    int ks = (gid>>9) & 1;
    int og = (gid>>10) & 3;
    int rest = gid >> 12;                // 0..47
    int kt = rest % 12;
    int ob = rest / 12;
    int k  = kt*64 + ks*32 + fg*8 + e;
    int oc = ob*64 + og*16 + fr;
    float x = cw[oc*768 + k];
    h16 hi = (h16)x;
    v21_whi[gid] = hi;
    v21_wlo[gid] = (h16)(x - (float)hi);
  } else if (b < 4976){
    // depth: [nf][ktI][fg][fr][e]
    int gid = (b-4864)*256 + tid;        // 0..28671
    int e   = gid & 7;
    int fr  = (gid>>3) & 15;
    int fg  = (gid>>7) & 3;
    int ktI = (gid>>9) & 7;
    int nf  = gid >> 12;                 // 0..6
    int o = nf*16 + fr;
    int c = ktI*32 + fg*8 + e;
    float x = (o < 105) ? dw[o*256 + c] : 0.f;
    h16 hi = (h16)x;
    v21_dwhi[gid] = hi;
    v21_dwlo[gid] = (h16)(x - (float)hi);
  } else if (b < 5120){
    // conv2: [nf][ktI][fg][fr][e], k-order = tap*64+ic, folded concat halves
    int gid = (b-4976)*256 + tid;
    if (gid < 36864){
      int e  = gid & 7;
      int fr = (gid>>3) & 15;
      int fg = (gid>>7) & 3;
      int t  = gid >> 9;
      int ktI = t % 18;
      int nf  = t / 18;
      int o = nf*16 + fr;
      int k = ktI*32 + fg*8 + e;
      int tap = k >> 6, ic = k & 63;
      float x = enc_w[o*1152 + ic*9 + tap] + enc_w[o*1152 + (ic+64)*9 + tap];
      h16 hi = (h16)x;
      v21_w2hi[gid] = hi;
      v21_w2lo[gid] = (h16)(x - (float)hi);
    }
  } else {
    int t = tid;
    if (t >= 24) return;
    double pr[9], it[9], r[9];
    for (int i=0;i<9;i++){
      pr[i] = (double)post_rots[t*9+i];
      it[i] = (double)intrins[t*9+i];
      r[i]  = (double)rots[t*9+i];
    }
    double ipr[9], iit[9];
    inv3_v11(pr, ipr); inv3_v11(it, iit);
    double* g = v11_geom + t*24;
    for (int i=0;i<3;i++) for(int j=0;j<3;j++){
      double s=0; for(int k=0;k<3;k++) s += r[i*3+k]*iit[k*3+j];
      g[9+i*3+j]=s;
    }
    for (int i=0;i<9;i++) g[i]   = ipr[i];
    for (int i=0;i<3;i++) g[18+i]= (double)post_trans[t*3+i];
    for (int i=0;i<3;i++) g[21+i]= (double)trans[t*3+i];
  }
}

// conv1 f16-split MFMA GEMM: block 64(M) x 64(N) x 64(K), 4 waves (2Mx2N).
// A: LDS (XOR swizzle) with register prefetch. B: DIRECT coalesced global
// fragment loads from fragment-order pack (no LDS). LDS = 16 KB.
// Grid 1056 1D, XCD-adjacency swizzle (4 ob-blocks of one pbase adjacent on one XCD).
__global__ __launch_bounds__(256) void conv1_v21(const float* img,
    const float* cb, const float* g1, const float* b1, const float* m1, const float* v1){
  __shared__ __align__(16) h16 Ah[8][64][8];    //  8 KB
  __shared__ __align__(16) h16 Al[8][64][8];    //  8 KB
  int tid  = threadIdx.x;
  int lane = tid & 63, wv = tid >> 6;
  int wr = wv >> 1, wc = wv & 1;          // wave grid 2(M) x 2(N)
  int bid = blockIdx.x;                   // 0..1055
  int xcd = bid & 7;
  int s   = bid >> 3;                     // 0..131
  int ob  = s & 3;
  int pb  = (s >> 2) + 33*xcd;            // 0..263
  int pbase = pb * 64;

  // A tasks: (pp = tid>>3, kc = tid&7); two rows pp0, pp0+32
  int pp0 = tid >> 3, kc0 = tid & 7;
  const float* ab[2];
  #pragma unroll
  for (int i=0;i<2;i++){
    int p = pbase + pp0 + 32*i;
    int im = p/704, pix = p%704;
    int ph = pix/44, pw = pix%44;
    ab[i] = img + (size_t)im*540672 + (size_t)ph*16*704 + pw*16;
  }

  // A prefetch registers
  float4 pa0[2], pa1[2];
  auto LOAD_A = [&](int ktI){
    int k0 = ktI*64 + kc0*8;
    int c = k0>>8, rem = k0&255, ky = rem>>4, kx = rem&15;
    size_t goff = (size_t)c*180224 + ky*704 + kx;
    #pragma unroll
    for (int i=0;i<2;i++){
      pa0[i] = *(const float4*)(ab[i] + goff);
      pa1[i] = *(const float4*)(ab[i] + goff + 4);
    }
  };

  f32x4 acc[2][2];
  #pragma unroll
  for (int mf=0;mf<2;mf++)
    #pragma unroll
    for (int nf=0;nf<2;nf++) acc[mf][nf] = (f32x4){0.f,0.f,0.f,0.f};

  int fr = lane & 15, fg = lane >> 4;
  int lo8 = lane*8;

  LOAD_A(0);

  for (int ktI=0; ktI<12; ktI++){
    __syncthreads();
    // write phase: split prefetched A regs -> LDS (XOR row swizzle)
    #pragma unroll
    for (int i=0;i<2;i++){
      float vv[8] = {pa0[i].x,pa0[i].y,pa0[i].z,pa0[i].w,
                     pa1[i].x,pa1[i].y,pa1[i].z,pa1[i].w};
      half8v hv, lv;
      #pragma unroll
      for (int e=0;e<8;e++){ h16 h=(h16)vv[e]; hv[e]=h; lv[e]=(h16)(vv[e]-(float)h); }
      int srow = (pp0 + 32*i) ^ kc0;
      *(half8v*)&Ah[kc0][srow][0] = hv;
      *(half8v*)&Al[kc0][srow][0] = lv;
    }
    __syncthreads();
    if (ktI < 11) LOAD_A(ktI+1);   // next tile's image loads fly under MFMA
    // B fragment base for this tile: [ob][kt] tile of 4096 halves
    int btile = (ob*12 + ktI) << 12;
    #pragma unroll
    for (int ks=0;ks<2;ks++){
      int kc = ks*4 + fg;
      half8v ah[2], al[2];
      #pragma unroll
      for (int mf=0;mf<2;mf++){
        int row = (wr*32 + mf*16 + fr) ^ kc;
        ah[mf] = *(const half8v*)&Ah[kc][row][0];
        al[mf] = *(const half8v*)&Al[kc][row][0];
      }
      #pragma unroll
      for (int nf=0;nf<2;nf++){
        int og = wc*2 + nf;
        int bidx = btile + ((og*2 + ks) << 9) + lo8;
        half8v bh = *(const half8v*)&v21_whi[bidx];
        half8v bl = *(const half8v*)&v21_wlo[bidx];
        #pragma unroll
        for (int mf=0;mf<2;mf++){
          acc[mf][nf] = __builtin_amdgcn_mfma_f32_16x16x32_f16(ah[mf], bh, acc[mf][nf], 0,0,0);
          acc[mf][nf] = __builtin_amdgcn_mfma_f32_16x16x32_f16(ah[mf], bl, acc[mf][nf], 0,0,0);
          acc[mf][nf] = __builtin_amdgcn_mfma_f32_16x16x32_f16(al[mf], bh, acc[mf][nf], 0,0,0);
        }
      }
    }
  }
  // epilogue: BN + ReLU, C layout col=lane&15, row=(lane>>4)*4+j
  int obase = ob * 64;
  #pragma unroll
  for (int nf=0;nf<2;nf++){
    int ch = obase + wc*32 + nf*16 + fr;
    float sc = g1[ch] / sqrtf(v1[ch] + 1e-5f);
    float sh = b1[ch] - m1[ch]*sc;
    float bi = cb[ch];
    #pragma unroll
    for (int mf=0;mf<2;mf++){
      #pragma unroll
      for (int j=0;j<4;j++){
        int pq = pbase + wr*32 + mf*16 + fg*4 + j;
        float t = (acc[mf][nf][j] + bi)*sc + sh;
        v11_xbuf[(size_t)pq*256 + ch] = t > 0.f ? t : 0.f;
      }
    }
  }
}

// depth head: A staged in LDS (one half8/thread), B DIRECT fragment-order global.
__global__ __launch_bounds__(256) void depth_v18(const float* db){
  __shared__ __align__(16) h16 Ah[4][64][8];    // 4 KB
  __shared__ __align__(16) h16 Al[4][64][8];
  __shared__ float sy[64*113];   // 28,928 B
  int tid = threadIdx.x;
  int lane = tid & 63, wv = tid >> 6;
  int pbase = blockIdx.x*64;
  int fr = lane & 15, fg = lane >> 4;
  int lo8 = lane*8;

  int app = tid & 63;            // A task: row fixed, kc = tid>>6
  int kcA = tid >> 6;
  const float* xsrc = &v11_xbuf[(size_t)(pbase+app)*256 + kcA*8];

  f32x4 acc[7];
  #pragma unroll
  for (int nf=0;nf<7;nf++) acc[nf] = (f32x4){0.f,0.f,0.f,0.f};

  for (int ktI=0; ktI<8; ktI++){
    __syncthreads();
    {
      float4 v0 = *(const float4*)(xsrc + ktI*32);
      float4 v1 = *(const float4*)(xsrc + ktI*32 + 4);
      float vv[8] = {v0.x,v0.y,v0.z,v0.w,v1.x,v1.y,v1.z,v1.w};
      half8v hv, lv;
      #pragma unroll
      for (int e=0;e<8;e++){ h16 h=(h16)vv[e]; hv[e]=h; lv[e]=(h16)(vv[e]-(float)h); }
      *(half8v*)&Ah[kcA][app][0] = hv;
      *(half8v*)&Al[kcA][app][0] = lv;
    }
    __syncthreads();
    int row = wv*16 + fr;
    half8v ah = *(const half8v*)&Ah[fg][row][0];
    half8v al = *(const half8v*)&Al[fg][row][0];
    #pragma unroll
    for (int nf=0;nf<7;nf++){
      int bidx = ((nf*8 + ktI) << 9) + lo8;
      half8v bh = *(const half8v*)&v21_dwhi[bidx];
      half8v bl = *(const half8v*)&v21_dwlo[bidx];
      acc[nf] = __builtin_amdgcn_mfma_f32_16x16x32_f16(ah, bh, acc[nf], 0,0,0);
      acc[nf] = __builtin_amdgcn_mfma_f32_16x16x32_f16(ah, bl, acc[nf], 0,0,0);
      acc[nf] = __builtin_amdgcn_mfma_f32_16x16x32_f16(al, bh, acc[nf], 0,0,0);
    }
  }
  // y -> LDS with bias; C layout col=lane&15, row=(lane>>4)*4+j
  #pragma unroll
  for (int nf=0;nf<7;nf++){
    int o = nf*16 + fr;
    if (o < 105){
      float bias = db[o];
      #pragma unroll
      for (int j=0;j<4;j++){
        int pp = wv*16 + fg*4 + j;
        sy[pp*113 + o] = acc[nf][j] + bias;
      }
    }
  }
  __syncthreads();
  // softmax over first 41 per patch (64 threads, one per patch)
  if (tid < 64){
    float* y = &sy[tid*113];
    float m = y[0];
    for (int i=1;i<41;i++) m = fmaxf(m, y[i]);
    float s = 0.f;
    for (int i=0;i<41;i++){ float e = expf(y[i]-m); y[i] = e; s += e; }
    float inv = 1.f/s;
    for (int i=0;i<41;i++) y[i] *= inv;
  }
  __syncthreads();
  // write depth + ctx (coalesced)
  for (int l = tid; l < 64*41; l += 256){
    int pp = l/41, dd = l%41;
    v11_depth[(size_t)(pbase+pp)*41 + dd] = sy[pp*113+dd];
  }
  for (int l = tid; l < 64*64; l += 256){
    int pp = l>>6, c = l&63;
    v11_ctx[(size_t)(pbase+pp)*64 + c] = sy[pp*113 + 41 + c];
  }
}

// voxel rank per point + skew-immune LDS histogram + per-point voxel position.
__global__ __launch_bounds__(256) void rank_v13(){
  __shared__ int lh[16384];
  int tid = threadIdx.x;
  for (int i = tid; i < 16384; i += 256) lh[i] = 0;
  __syncthreads();
  int base = blockIdx.x*1024;
  int rk[4], lp[4];
  #pragma unroll
  for (int k=0;k<4;k++){
    int idx = base + k*256 + tid;
    rk[k] = -1; lp[k] = 0;
    if (idx < NPTS){
      int im = idx / 28864;
      int r  = idx % 28864;
      int d  = r / 704; int pix = r % 704;
      int h = pix / 44, w = pix % 44;
      const double* g = v11_geom + im*24;
      double fx = (double)w * (703.0/43.0);
      double fy = (double)h * 17.0;
      double fz = 4.0 + (double)d;
      double px = fx - g[18], py = fy - g[19], pz = fz - g[20];
      double q0 = g[0]*px + g[1]*py + g[2]*pz;
      double q1 = g[3]*px + g[4]*py + g[5]*pz;
      double q2 = g[6]*px + g[7]*py + g[8]*pz;
      q0 *= q2; q1 *= q2;
      double o0 = g[9]*q0  + g[10]*q1 + g[11]*q2 + g[21];
      double o1 = g[12]*q0 + g[13]*q1 + g[14]*q2 + g[22];
      double o2 = g[15]*q0 + g[16]*q1 + g[17]*q2 + g[23];
      int cx = (int)((o0 + 51.2)/0.8);
      int cy = (int)((o1 + 51.2)/0.8);
      int cz = (int)((o2 + 10.0)/20.0);
      int rank = cx + cy*128 + cz*16384;
      if (rank >= 0 && rank < 16384){
        rk[k] = rank;
        lp[k] = atomicAdd(&lh[rank], 1);   // position within block's local count
      }
    }
  }
  __syncthreads();
  // flush nonzero bins; lh[bin] becomes this block's global base for that bin
  for (int i = tid; i < 16384; i += 256){
    int h = lh[i];
    if (h) lh[i] = atomicAdd(&v12_cnt[i], h);
  }
  __syncthreads();
  #pragma unroll
  for (int k=0;k<4;k++){
    int idx = base + k*256 + tid;
    if (idx < NPTS){
      v11_ranks[idx] = rk[k];
      if (rk[k] >= 0) v12_pos[idx] = lh[rk[k]] + lp[k];
    }
  }
}

// exclusive scan over 16384 counts -> offsets + total, single block
__global__ __launch_bounds__(256) void scan_v13(){
  __shared__ int part[256];
  int t = threadIdx.x;
  int base = t*64;
  int s = 0;
  for (int i=0;i<64;i++) s += v12_cnt[base+i];
  part[t] = s;
  __syncthreads();
  if (t == 0){
    int run = 0;
    for (int i=0;i<256;i++){ int v = part[i]; part[i] = run; run += v; }
    v12_total = run;
  }
  __syncthreads();
  int run = part[t];
  for (int i=0;i<64;i++){
    v12_off[base+i] = run;
    run += v12_cnt[base+i];
  }
}

// place points into rank-sorted order — NO atomics (position precomputed)
__global__ __launch_bounds__(256) void fill_v13(){
  int idx = blockIdx.x*256 + threadIdx.x;
  if (idx >= NPTS) return;
  int rank = v11_ranks[idx];
  if (rank < 0) return;
  int im = idx / 28864;
  int r  = idx % 28864;
  int d  = r / 704; int pix = r % 704;
  int p  = im*704 + pix;
  int pos = v12_off[rank] + v12_pos[idx];
  v12_sorted[pos] = make_int2((p<<6) | d, rank);
}

// work-balanced segmented reduction: one wave per 64 sorted points, lane = channel.
__global__ __launch_bounds__(256) void gather_v13(){
  int total = v12_total;
  int w = threadIdx.x >> 6;
  int chunk = blockIdx.x*256 + w*64;
  if (chunk >= total) return;
  int lane = threadIdx.x & 63;
  int n = total - chunk; if (n > 64) n = 64;
  // per-lane coalesced load of one point (packed, rank) + its depth weight
  int pv = 0, rv = -1;
  float dv = 0.f;
  if (lane < n){
    int2 sr = v12_sorted[chunk + lane];
    pv = sr.x; rv = sr.y;
    dv = v11_depth[(pv>>6)*41 + (pv & 63)];
  }
  float acc = 0.f;
  int cur = __shfl(rv, 0);
  for (int i = 0; i < n; i++){
    int rk = __shfl(rv, i);
    int pp = __shfl(pv, i) >> 6;
    float dd = __shfl(dv, i);
    if (rk != cur){                       // wave-uniform branch
      atomicAdd(&v11_bev[(size_t)cur*64 + lane], acc);
      acc = 0.f; cur = rk;
    }
    acc += v11_ctx[(pp<<6) | lane] * dd;  // coalesced 256B row read
  }
  atomicAdd(&v11_bev[(size_t)cur*64 + lane], acc);
}

// conv2 3x3 SAME f16-split implicit GEMM + BN2 + ReLU + 7x64 head.
// A: LDS stage (boundary-zero). B: DIRECT fragment-order global.
// bevout folded: center-tap (tap==4) staging writes out1 = transpose(bev).
__global__ __launch_bounds__(256) void conv2_v19(
    const float* eb, const float* g2, const float* b2_, const float* m2, const float* v2,
    const float* hw, const float* hb, float* out0, float* out1){
  __shared__ __align__(16) h16 Ah[4][64][8];    // 4 KB
  __shared__ __align__(16) h16 Al[4][64][8];
  __shared__ float sfeat[64*68]; // 17,408 B
  __shared__ float hred[4*64*7]; //  7,168 B
  int tid = threadIdx.x;
  int lane = tid & 63, wv = tid >> 6;
  int bx = blockIdx.x & 15, by = blockIdx.x >> 4;
  int fr = lane & 15, fg = lane >> 4;
  int lo8 = lane*8;

  int app = tid & 63;            // A task: row fixed, kc = tid>>6
  int kcT = tid >> 6;
  int apy = app >> 3, apx = app & 7;

  f32x4 acc[4];
  #pragma unroll
  for (int nf=0;nf<4;nf++) acc[nf] = (f32x4){0.f,0.f,0.f,0.f};

  for (int ktI=0; ktI<18; ktI++){
    int kt = ktI*32;
    int tap = kt >> 6, ic0 = kt & 32;
    int dy = tap/3 - 1, dx = tap%3 - 1;
    __syncthreads();
    // stage A: one half8 (8 channels) per thread from bev (boundary-zero)
    {
      int gy = by*8 + apy + dy, gx = bx*8 + apx + dx;
      float4 v0 = {0.f,0.f,0.f,0.f}, v1 = {0.f,0.f,0.f,0.f};
      if (gy>=0 && gy<128 && gx>=0 && gx<128){
        const float* src = &v11_bev[(size_t)(gy*128+gx)*64 + ic0 + kcT*8];
        v0 = *(const float4*)src;
        v1 = *(const float4*)(src+4);
      }
      float vv[8] = {v0.x,v0.y,v0.z,v0.w,v1.x,v1.y,v1.z,v1.w};
      // folded bevout: center tap passes each (pixel, channel) exactly once
      if (tap == 4){
        int gyc = by*8 + apy, gxc = bx*8 + apx;
        int ch0 = ic0 + kcT*8;
        #pragma unroll
        for (int q=0;q<8;q++)
          out1[(ch0+q)*16384 + gyc*128 + gxc] = vv[q];
      }
      half8v hv, lv;
      #pragma unroll
      for (int e=0;e<8;e++){ h16 h=(h16)vv[e]; hv[e]=h; lv[e]=(h16)(vv[e]-(float)h); }
      *(half8v*)&Ah[kcT][app][0] = hv;
      *(half8v*)&Al[kcT][app][0] = lv;
    }
    __syncthreads();
    int row = wv*16 + fr;
    half8v ah = *(const half8v*)&Ah[fg][row][0];
    half8v al = *(const half8v*)&Al[fg][row][0];
    #pragma unroll
    for (int nf=0;nf<4;nf++){
      int bidx = ((nf*18 + ktI) << 9) + lo8;
      half8v bh = *(const half8v*)&v21_w2hi[bidx];
      half8v bl = *(const half8v*)&v21_w2lo[bidx];
      acc[nf] = __builtin_amdgcn_mfma_f32_16x16x32_f16(ah, bh, acc[nf], 0,0,0);
      acc[nf] = __builtin_amdgcn_mfma_f32_16x16x32_f16(ah, bl, acc[nf], 0,0,0);
      acc[nf] = __builtin_amdgcn_mfma_f32_16x16x32_f16(al, bh, acc[nf], 0,0,0);
    }
  }
  // BN + ReLU -> sfeat; C layout col=lane&15, row=(lane>>4)*4+j
  #pragma unroll
  for (int nf=0;nf<4;nf++){
    int ch = nf*16 + fr;
    float sc = g2[ch]/sqrtf(v2[ch]+1e-5f);
    float sh = b2_[ch] - m2[ch]*sc;
    float bi = eb[ch];
    #pragma unroll
    for (int j=0;j<4;j++){
      int pp = wv*16 + fg*4 + j;
      float t = (acc[nf][j] + bi)*sc + sh;
      sfeat[pp*68 + ch] = t > 0.f ? t : 0.f;
    }
  }
  __syncthreads();
  // head: 7x64, partial over 16 channels per og, LDS reduce
  int og = tid >> 6, pix = tid & 63;
  float part[7];
  #pragma unroll
  for (int o=0;o<7;o++) part[o]=0.f;
  #pragma unroll
  for (int j=0;j<16;j++){
    int oc = og*16 + j;
    float v = sfeat[pix*68 + oc];
    #pragma unroll
    for (int o=0;o<7;o++) part[o] += hw[o*64+oc]*v;
  }
  #pragma unroll
  for (int o=0;o<7;o++) hred[(og*64+pix)*7+o] = part[o];
  __syncthreads();
  if (og == 0){
    int gy = by*8 + (pix>>3), gx = bx*8 + (pix&7);
    #pragma unroll
    for (int o=0;o<7;o++){
      float s = hred[pix*7+o] + hred[(64+pix)*7+o] + hred[(128+pix)*7+o]
              + hred[(192+pix)*7+o] + hb[o];
      out0[o*16384 + gy*128 + gx] = s;
    }
  }
}

extern "C" void kernel_launch(void* const* d_in, const int* in_sizes, int n_in,
                              void* d_out, int out_size, void* d_ws, size_t ws_size,
                              hipStream_t stream){
  const float* imgs       = (const float*)d_in[0];
  const float* rots       = (const float*)d_in[1];
  const float* trans      = (const float*)d_in[2];
  const float* intrins    = (const float*)d_in[3];
  const float* post_rots  = (const float*)d_in[4];
  const float* post_trans = (const float*)d_in[5];
  const float* conv_w     = (const float*)d_in[6];
  const float* conv_b     = (const float*)d_in[7];
  const float* bn1_g      = (const float*)d_in[8];
  const float* bn1_b      = (const float*)d_in[9];
  const float* bn1_m      = (const float*)d_in[10];
  const float* bn1_v      = (const float*)d_in[11];
  const float* depth_w    = (const float*)d_in[12];
  const float* depth_b    = (const float*)d_in[13];
  const float* enc_w      = (const float*)d_in[14];
  const float* enc_b      = (const float*)d_in[15];
  const float* bn2_g      = (const float*)d_in[16];
  const float* bn2_b      = (const float*)d_in[17];
  const float* bn2_m      = (const float*)d_in[18];
  const float* bn2_v      = (const float*)d_in[19];
  const float* head_w     = (const float*)d_in[20];
  const float* head_b     = (const float*)d_in[21];

  float* out0 = (float*)d_out;          // (1,7,128,128)
  float* out1 = out0 + 114688;          // (1,64,128,128)

  prep_v21<<<5121, 256, 0, stream>>>(conv_w, depth_w, enc_w,
                                     rots, trans, intrins, post_rots, post_trans);
  conv1_v21<<<1056, 256, 0, stream>>>(imgs, conv_b, bn1_g, bn1_b, bn1_m, bn1_v);
  depth_v18<<<264, 256, 0, stream>>>(depth_b);
  rank_v13<<<(NPTS+1023)/1024, 256, 0, stream>>>();
  scan_v13<<<1, 256, 0, stream>>>();
  fill_v13<<<NPTS/256, 256, 0, stream>>>();
  gather_v13<<<NPTS/256, 256, 0, stream>>>();
  conv2_v19<<<256, 256, 0, stream>>>(enc_b, bn2_g, bn2_b, bn2_m, bn2_v,
                                     head_w, head_b, out0, out1);
}

// Round 13
// 269.281 us; speedup vs baseline: 1.0343x; 1.0343x over previous
//
#include <hip/hip_runtime.h>
#include <hip/hip_bf16.h>
#include <hip/hip_fp16.h>

#define NPTS 692736      // 24*41*16*44
#define NPATCH 16896     // 24*16*44

typedef _Float16 h16;
typedef __attribute__((ext_vector_type(4))) _Float16 half4v;
typedef __attribute__((ext_vector_type(8))) _Float16 half8v;
typedef __attribute__((ext_vector_type(4))) float f32x4;

// ---------- module-scope device globals ----------
__device__ float  v11_xbuf[NPATCH*256];
__device__ float  v11_ctx[NPATCH*64];
__device__ float  v11_depth[NPATCH*41];
__device__ int    v11_ranks[NPTS];
__device__ float  v11_bev[16384*64];
__device__ double v11_geom[24*24];

// conv1 weights packed in MFMA-fragment order: [ob(4)][kt(12)][og16(4)][ks(2)][fg(4)][fr(16)][e(8)]
__device__ h16    v21_whi[196608];
__device__ h16    v21_wlo[196608];

// f16 hi/lo split depth weights, padded [112][256] ([o][c])
__device__ h16    v15_dwhi[112*256];
__device__ h16    v15_dwlo[112*256];

// f16 hi/lo split folded conv2 weights, [o][k] with k = tap*64 + ic
__device__ h16    v16_w2hi[64*576];
__device__ h16    v16_w2lo[64*576];

// counting-sort state for scatter->gather inversion
__device__ int    v12_cnt[16384];
__device__ int    v12_off[16384];
__device__ int    v12_pos[NPTS];       // position within own voxel
__device__ int2   v12_sorted[NPTS];    // (packed (p<<6)|d, rank) in rank order
__device__ int    v12_total;

__device__ __forceinline__ void inv3_v11(const double* m, double* o){
  double a=m[0],b=m[1],c=m[2],d=m[3],e=m[4],f=m[5],g=m[6],h=m[7],i=m[8];
  double A = e*i - f*h, B = -(d*i - f*g), C = d*h - e*g;
  double det = a*A + b*B + c*C;
  double id = 1.0/det;
  o[0]=A*id;            o[1]=-(b*i - c*h)*id; o[2]=(b*f - c*e)*id;
  o[3]=B*id;            o[4]=(a*i - c*g)*id;  o[5]=-(a*f - c*d)*id;
  o[6]=C*id;            o[7]=-(a*h - b*g)*id; o[8]=(a*e - b*d)*id;
}

// fused prep: zero + conv1 fragment-order pack + depth/conv2 splits + geom
// grid = 4096 + 768 + 112 + 144 + 1 = 5121
__global__ void prep_v22(const float* cw, const float* dw, const float* enc_w,
                         const float* rots, const float* trans, const float* intrins,
                         const float* post_rots, const float* post_trans){
  int b = blockIdx.x;
  int tid = threadIdx.x;
  if (b < 4096){
    int gid = b*256 + tid;
    v11_bev[gid] = 0.f;
    if (gid < 16384) v12_cnt[gid] = 0;
  } else if (b < 4864){
    // conv1: [ob][kt][og][ks][fg][fr][e]
    int gid = (b-4096)*256 + tid;        // 0..196607
    int e  = gid & 7;
    int fr = (gid>>3) & 15;
    int fg = (gid>>7) & 3;
    int ks = (gid>>9) & 1;
    int og = (gid>>10) & 3;
    int rest = gid >> 12;                // 0..47
    int kt = rest % 12;
    int ob = rest / 12;
    int k  = kt*64 + ks*32 + fg*8 + e;
    int oc = ob*64 + og*16 + fr;
    float x = cw[oc*768 + k];
    h16 hi = (h16)x;
    v21_whi[gid] = hi;
    v21_wlo[gid] = (h16)(x - (float)hi);
  } else if (b < 4976){
    // split depth_w [105][256] -> padded [112][256]
    int gid = (b-4864)*256 + tid;        // 0..28671
    int o = gid >> 8, c = gid & 255;
    float x = (o < 105) ? dw[o*256 + c] : 0.f;
    h16 hi = (h16)x;
    v15_dwhi[gid] = hi;
    v15_dwlo[gid] = (h16)(x - (float)hi);
  } else if (b < 5120){
    // fold enc_w concat halves, k-order = tap*64+ic
    int gid = (b-4976)*256 + tid;
    if (gid < 36864){
      int o = gid / 576; int k = gid % 576;
      int tap = k >> 6, ic = k & 63;
      float x = enc_w[o*1152 + ic*9 + tap] + enc_w[o*1152 + (ic+64)*9 + tap];
      h16 hi = (h16)x;
      v16_w2hi[gid] = hi;
      v16_w2lo[gid] = (h16)(x - (float)hi);
    }
  } else {
    int t = tid;
    if (t >= 24) return;
    double pr[9], it[9], r[9];
    for (int i=0;i<9;i++){
      pr[i] = (double)post_rots[t*9+i];
      it[i] = (double)intrins[t*9+i];
      r[i]  = (double)rots[t*9+i];
    }
    double ipr[9], iit[9];
    inv3_v11(pr, ipr); inv3_v11(it, iit);
    double* g = v11_geom + t*24;
    for (int i=0;i<3;i++) for(int j=0;j<3;j++){
      double s=0; for(int k=0;k<3;k++) s += r[i*3+k]*iit[k*3+j];
      g[9+i*3+j]=s;
    }
    for (int i=0;i<9;i++) g[i]   = ipr[i];
    for (int i=0;i<3;i++) g[18+i]= (double)post_trans[t*3+i];
    for (int i=0;i<3;i++) g[21+i]= (double)trans[t*3+i];
  }
}

// conv1 f16-split MFMA GEMM: block 64(M) x 64(N) x 64(K), 4 waves (2Mx2N).
// A: LDS (XOR swizzle) + register prefetch. B: direct fragment-order global
// loads, DOUBLE-BUFFERED in registers (tile t+1's loads issued under tile t's
// MFMA) so L2 latency is off the MFMA critical path. Full unroll keeps the
// parity-indexed buffers in registers. LDS = 16 KB.
__global__ __launch_bounds__(256) void conv1_v22(const float* img,
    const float* cb, const float* g1, const float* b1, const float* m1, const float* v1){
  __shared__ __align__(16) h16 Ah[8][64][8];    //  8 KB
  __shared__ __align__(16) h16 Al[8][64][8];    //  8 KB
  int tid  = threadIdx.x;
  int lane = tid & 63, wv = tid >> 6;
  int wr = wv >> 1, wc = wv & 1;          // wave grid 2(M) x 2(N)
  int bid = blockIdx.x;                   // 0..1055
  int xcd = bid & 7;
  int s   = bid >> 3;                     // 0..131
  int ob  = s & 3;
  int pb  = (s >> 2) + 33*xcd;            // 0..263
  int pbase = pb * 64;

  // A tasks: (pp = tid>>3, kc = tid&7); two rows pp0, pp0+32
  int pp0 = tid >> 3, kc0 = tid & 7;
  const float* ab[2];
  #pragma unroll
  for (int i=0;i<2;i++){
    int p = pbase + pp0 + 32*i;
    int im = p/704, pix = p%704;
    int ph = pix/44, pw = pix%44;
    ab[i] = img + (size_t)im*540672 + (size_t)ph*16*704 + pw*16;
  }

  int fr = lane & 15, fg = lane >> 4;
  int lo8 = lane*8;

  // prefetch registers
  float4 pa0[2], pa1[2];
  half8v pbh[2][4], pbl[2][4];   // [parity][ks*2+nf]

  auto LOAD_A = [&](int ktI){
    int k0 = ktI*64 + kc0*8;
    int c = k0>>8, rem = k0&255, ky = rem>>4, kx = rem&15;
    size_t goff = (size_t)c*180224 + ky*704 + kx;
    #pragma unroll
    for (int i=0;i<2;i++){
      pa0[i] = *(const float4*)(ab[i] + goff);
      pa1[i] = *(const float4*)(ab[i] + goff + 4);
    }
  };
  auto LOAD_B = [&](int ktI, int par){
    int btile = (ob*12 + ktI) << 12;
    #pragma unroll
    for (int ks=0;ks<2;ks++)
      #pragma unroll
      for (int nf=0;nf<2;nf++){
        int og = wc*2 + nf;
        int bidx = btile + ((og*2 + ks) << 9) + lo8;
        pbh[par][ks*2+nf] = *(const half8v*)&v21_whi[bidx];
        pbl[par][ks*2+nf] = *(const half8v*)&v21_wlo[bidx];
      }
  };

  f32x4 acc[2][2];
  #pragma unroll
  for (int mf=0;mf<2;mf++)
    #pragma unroll
    for (int nf=0;nf<2;nf++) acc[mf][nf] = (f32x4){0.f,0.f,0.f,0.f};

  LOAD_A(0); LOAD_B(0, 0);

  #pragma unroll
  for (int ktI=0; ktI<12; ktI++){
    int par = ktI & 1;
    __syncthreads();
    // write phase: split prefetched A regs -> LDS (XOR row swizzle)
    #pragma unroll
    for (int i=0;i<2;i++){
      float vv[8] = {pa0[i].x,pa0[i].y,pa0[i].z,pa0[i].w,
                     pa1[i].x,pa1[i].y,pa1[i].z,pa1[i].w};
      half8v hv, lv;
      #pragma unroll
      for (int e=0;e<8;e++){ h16 h=(h16)vv[e]; hv[e]=h; lv[e]=(h16)(vv[e]-(float)h); }
      int srow = (pp0 + 32*i) ^ kc0;
      *(half8v*)&Ah[kc0][srow][0] = hv;
      *(half8v*)&Al[kc0][srow][0] = lv;
    }
    __syncthreads();
    // issue next tile's A image loads + B fragment loads (fly under MFMA)
    if (ktI < 11){ LOAD_A(ktI+1); LOAD_B(ktI+1, par^1); }
    #pragma unroll
    for (int ks=0;ks<2;ks++){
      int kc = ks*4 + fg;
      half8v ah[2], al[2];
      #pragma unroll
      for (int mf=0;mf<2;mf++){
        int row = (wr*32 + mf*16 + fr) ^ kc;
        ah[mf] = *(const half8v*)&Ah[kc][row][0];
        al[mf] = *(const half8v*)&Al[kc][row][0];
      }
      #pragma unroll
      for (int nf=0;nf<2;nf++){
        half8v bh = pbh[par][ks*2+nf];
        half8v bl = pbl[par][ks*2+nf];
        #pragma unroll
        for (int mf=0;mf<2;mf++){
          acc[mf][nf] = __builtin_amdgcn_mfma_f32_16x16x32_f16(ah[mf], bh, acc[mf][nf], 0,0,0);
          acc[mf][nf] = __builtin_amdgcn_mfma_f32_16x16x32_f16(ah[mf], bl, acc[mf][nf], 0,0,0);
          acc[mf][nf] = __builtin_amdgcn_mfma_f32_16x16x32_f16(al[mf], bh, acc[mf][nf], 0,0,0);
        }
      }
    }
  }
  // epilogue: BN + ReLU, C layout col=lane&15, row=(lane>>4)*4+j
  int obase = ob * 64;
  #pragma unroll
  for (int nf=0;nf<2;nf++){
    int ch = obase + wc*32 + nf*16 + fr;
    float sc = g1[ch] / sqrtf(v1[ch] + 1e-5f);
    float sh = b1[ch] - m1[ch]*sc;
    float bi = cb[ch];
    #pragma unroll
    for (int mf=0;mf<2;mf++){
      #pragma unroll
      for (int j=0;j<4;j++){
        int pq = pbase + wr*32 + mf*16 + fg*4 + j;
        float t = (acc[mf][nf][j] + bi)*sc + sh;
        v11_xbuf[(size_t)pq*256 + ch] = t > 0.f ? t : 0.f;
      }
    }
  }
}

// depth head as f16-split MFMA GEMM: y[16896x105] = x[16896x256] * W^T[256x105]
// block = 64 patches, N padded to 112, K=256, BK=32 with [kc][row][8] LDS layout.
__global__ __launch_bounds__(256) void depth_v16(const float* db){
  __shared__ __align__(16) h16 Ah[4][64][8];    // 4 KB
  __shared__ __align__(16) h16 Al[4][64][8];
  __shared__ __align__(16) h16 Bh[4][112][8];   // 7 KB
  __shared__ __align__(16) h16 Bl[4][112][8];
  __shared__ float sy[64*113];   // 28,928 B
  int tid = threadIdx.x;
  int lane = tid & 63, wv = tid >> 6;
  int pbase = blockIdx.x*64;
  int fr = lane & 15, fg = lane >> 4;

  int app = tid & 63;            // A task: row fixed, kc = tid>>6
  int kcA = tid >> 6;
  const float* xsrc = &v11_xbuf[(size_t)(pbase+app)*256 + kcA*8];

  f32x4 acc[7];
  #pragma unroll
  for (int nf=0;nf<7;nf++) acc[nf] = (f32x4){0.f,0.f,0.f,0.f};

  for (int kt=0; kt<256; kt+=32){
    __syncthreads();
    // stage A from fp32 xbuf with in-flight hi/lo split (one half8 row/thread)
    {
      float4 v0 = *(const float4*)(xsrc + kt);
      float4 v1 = *(const float4*)(xsrc + kt + 4);
      float vv[8] = {v0.x,v0.y,v0.z,v0.w,v1.x,v1.y,v1.z,v1.w};
      half8v hv, lv;
      #pragma unroll
      for (int e=0;e<8;e++){ h16 h=(h16)vv[e]; hv[e]=h; lv[e]=(h16)(vv[e]-(float)h); }
      *(half8v*)&Ah[kcA][app][0] = hv;
      *(half8v*)&Al[kcA][app][0] = lv;
    }
    // stage W (pre-split, padded rows zero): 448 tasks, kc = l/112, o = l%112
    for (int l = tid; l < 448; l += 256){
      int kc = l/112, o = l%112;
      *(half8v*)&Bh[kc][o][0] = *(const half8v*)&v15_dwhi[o*256 + kt + kc*8];
      *(half8v*)&Bl[kc][o][0] = *(const half8v*)&v15_dwlo[o*256 + kt + kc*8];
    }
    __syncthreads();
    int row = wv*16 + fr;
    half8v ah = *(const half8v*)&Ah[fg][row][0];
    half8v al = *(const half8v*)&Al[fg][row][0];
    #pragma unroll
    for (int nf=0;nf<7;nf++){
      int col = nf*16 + fr;
      half8v bh = *(const half8v*)&Bh[fg][col][0];
      half8v bl = *(const half8v*)&Bl[fg][col][0];
      acc[nf] = __builtin_amdgcn_mfma_f32_16x16x32_f16(ah, bh, acc[nf], 0,0,0);
      acc[nf] = __builtin_amdgcn_mfma_f32_16x16x32_f16(ah, bl, acc[nf], 0,0,0);
      acc[nf] = __builtin_amdgcn_mfma_f32_16x16x32_f16(al, bh, acc[nf], 0,0,0);
    }
  }
  // y -> LDS with bias; C layout col=lane&15, row=(lane>>4)*4+j
  #pragma unroll
  for (int nf=0;nf<7;nf++){
    int o = nf*16 + fr;
    if (o < 105){
      float bias = db[o];
      #pragma unroll
      for (int j=0;j<4;j++){
        int pp = wv*16 + fg*4 + j;
        sy[pp*113 + o] = acc[nf][j] + bias;
      }
    }
  }
  __syncthreads();
  // softmax over first 41 per patch (64 threads, one per patch)
  if (tid < 64){
    float* y = &sy[tid*113];
    float m = y[0];
    for (int i=1;i<41;i++) m = fmaxf(m, y[i]);
    float s = 0.f;
    for (int i=0;i<41;i++){ float e = expf(y[i]-m); y[i] = e; s += e; }
    float inv = 1.f/s;
    for (int i=0;i<41;i++) y[i] *= inv;
  }
  __syncthreads();
  // write depth + ctx (coalesced)
  for (int l = tid; l < 64*41; l += 256){
    int pp = l/41, dd = l%41;
    v11_depth[(size_t)(pbase+pp)*41 + dd] = sy[pp*113+dd];
  }
  for (int l = tid; l < 64*64; l += 256){
    int pp = l>>6, c = l&63;
    v11_ctx[(size_t)(pbase+pp)*64 + c] = sy[pp*113 + 41 + c];
  }
}

// voxel rank per point + skew-immune LDS histogram + per-point voxel position.
__global__ __launch_bounds__(256) void rank_v13(){
  __shared__ int lh[16384];
  int tid = threadIdx.x;
  for (int i = tid; i < 16384; i += 256) lh[i] = 0;
  __syncthreads();
  int base = blockIdx.x*1024;
  int rk[4], lp[4];
  #pragma unroll
  for (int k=0;k<4;k++){
    int idx = base + k*256 + tid;
    rk[k] = -1; lp[k] = 0;
    if (idx < NPTS){
      int im = idx / 28864;
      int r  = idx % 28864;
      int d  = r / 704; int pix = r % 704;
      int h = pix / 44, w = pix % 44;
      const double* g = v11_geom + im*24;
      double fx = (double)w * (703.0/43.0);
      double fy = (double)h * 17.0;
      double fz = 4.0 + (double)d;
      double px = fx - g[18], py = fy - g[19], pz = fz - g[20];
      double q0 = g[0]*px + g[1]*py + g[2]*pz;
      double q1 = g[3]*px + g[4]*py + g[5]*pz;
      double q2 = g[6]*px + g[7]*py + g[8]*pz;
      q0 *= q2; q1 *= q2;
      double o0 = g[9]*q0  + g[10]*q1 + g[11]*q2 + g[21];
      double o1 = g[12]*q0 + g[13]*q1 + g[14]*q2 + g[22];
      double o2 = g[15]*q0 + g[16]*q1 + g[17]*q2 + g[23];
      int cx = (int)((o0 + 51.2)/0.8);
      int cy = (int)((o1 + 51.2)/0.8);
      int cz = (int)((o2 + 10.0)/20.0);
      int rank = cx + cy*128 + cz*16384;
      if (rank >= 0 && rank < 16384){
        rk[k] = rank;
        lp[k] = atomicAdd(&lh[rank], 1);   // position within block's local count
      }
    }
  }
  __syncthreads();
  // flush nonzero bins; lh[bin] becomes this block's global base for that bin
  for (int i = tid; i < 16384; i += 256){
    int h = lh[i];
    if (h) lh[i] = atomicAdd(&v12_cnt[i], h);
  }
  __syncthreads();
  #pragma unroll
  for (int k=0;k<4;k++){
    int idx = base + k*256 + tid;
    if (idx < NPTS){
      v11_ranks[idx] = rk[k];
      if (rk[k] >= 0) v12_pos[idx] = lh[rk[k]] + lp[k];
    }
  }
}

// exclusive scan over 16384 counts -> offsets + total, single block
__global__ __launch_bounds__(256) void scan_v13(){
  __shared__ int part[256];
  int t = threadIdx.x;
  int base = t*64;
  int s = 0;
  for (int i=0;i<64;i++) s += v12_cnt[base+i];
  part[t] = s;
  __syncthreads();
  if (t == 0){
    int run = 0;
    for (int i=0;i<256;i++){ int v = part[i]; part[i] = run; run += v; }
    v12_total = run;
  }
  __syncthreads();
  int run = part[t];
  for (int i=0;i<64;i++){
    v12_off[base+i] = run;
    run += v12_cnt[base+i];
  }
}

// place points into rank-sorted order — NO atomics (position precomputed)
__global__ __launch_bounds__(256) void fill_v13(){
  int idx = blockIdx.x*256 + threadIdx.x;
  if (idx >= NPTS) return;
  int rank = v11_ranks[idx];
  if (rank < 0) return;
  int im = idx / 28864;
  int r  = idx % 28864;
  int d  = r / 704; int pix = r % 704;
  int p  = im*704 + pix;
  int pos = v12_off[rank] + v12_pos[idx];
  v12_sorted[pos] = make_int2((p<<6) | d, rank);
}

// work-balanced segmented reduction: one wave per 64 sorted points, lane = channel.
__global__ __launch_bounds__(256) void gather_v13(){
  int total = v12_total;
  int w = threadIdx.x >> 6;
  int chunk = blockIdx.x*256 + w*64;
  if (chunk >= total) return;
  int lane = threadIdx.x & 63;
  int n = total - chunk; if (n > 64) n = 64;
  // per-lane coalesced load of one point (packed, rank) + its depth weight
  int pv = 0, rv = -1;
  float dv = 0.f;
  if (lane < n){
    int2 sr = v12_sorted[chunk + lane];
    pv = sr.x; rv = sr.y;
    dv = v11_depth[(pv>>6)*41 + (pv & 63)];
  }
  float acc = 0.f;
  int cur = __shfl(rv, 0);
  for (int i = 0; i < n; i++){
    int rk = __shfl(rv, i);
    int pp = __shfl(pv, i) >> 6;
    float dd = __shfl(dv, i);
    if (rk != cur){                       // wave-uniform branch
      atomicAdd(&v11_bev[(size_t)cur*64 + lane], acc);
      acc = 0.f; cur = rk;
    }
    acc += v11_ctx[(pp<<6) | lane] * dd;  // coalesced 256B row read
  }
  atomicAdd(&v11_bev[(size_t)cur*64 + lane], acc);
}

// bev output: [yx][c] -> out1[c][y][x] fp32
__global__ void bevout_v11(float* out1){
  int gid = blockIdx.x*256 + threadIdx.x;
  int c  = gid >> 14;
  int yx = gid & 16383;
  out1[gid] = v11_bev[(size_t)yx*64 + c];
}

// conv2 3x3 SAME as f16-split implicit-GEMM MFMA + BN2 + ReLU + 7x64 head.
// Block = 8x8 pixel tile (M=64) x N=64, K=576 (tap*64+ic), [kc][row][8] LDS layout.
__global__ __launch_bounds__(256) void conv2_v17(
    const float* eb, const float* g2, const float* b2_, const float* m2, const float* v2,
    const float* hw, const float* hb, float* out0){
  __shared__ __align__(16) h16 Ah[4][64][8];    // 4 KB
  __shared__ __align__(16) h16 Al[4][64][8];
  __shared__ __align__(16) h16 Bh[4][64][8];
  __shared__ __align__(16) h16 Bl[4][64][8];
  __shared__ float sfeat[64*68]; // 17,408 B
  __shared__ float hred[4*64*7]; //  7,168 B
  int tid = threadIdx.x;
  int lane = tid & 63, wv = tid >> 6;
  int bx = blockIdx.x & 15, by = blockIdx.x >> 4;
  int fr = lane & 15, fg = lane >> 4;

  int app = tid & 63;            // A/B task: row fixed, kc = tid>>6
  int kcT = tid >> 6;
  int apy = app >> 3, apx = app & 7;

  f32x4 acc[4];
  #pragma unroll
  for (int nf=0;nf<4;nf++) acc[nf] = (f32x4){0.f,0.f,0.f,0.f};

  for (int kt=0; kt<576; kt+=32){
    int tap = kt >> 6, ic0 = kt & 32;
    int dy = tap/3 - 1, dx = tap%3 - 1;
    __syncthreads();
    // stage A: one half8 (8 channels) per thread from bev (boundary-zero)
    {
      int gy = by*8 + apy + dy, gx = bx*8 + apx + dx;
      float4 v0 = {0.f,0.f,0.f,0.f}, v1 = {0.f,0.f,0.f,0.f};
      if (gy>=0 && gy<128 && gx>=0 && gx<128){
        const float* src = &v11_bev[(size_t)(gy*128+gx)*64 + ic0 + kcT*8];
        v0 = *(const float4*)src;
        v1 = *(const float4*)(src+4);
      }
      float vv[8] = {v0.x,v0.y,v0.z,v0.w,v1.x,v1.y,v1.z,v1.w};
      half8v hv, lv;
      #pragma unroll
      for (int e=0;e<8;e++){ h16 h=(h16)vv[e]; hv[e]=h; lv[e]=(h16)(vv[e]-(float)h); }
      *(half8v*)&Ah[kcT][app][0] = hv;
      *(half8v*)&Al[kcT][app][0] = lv;
    }
    // stage W: one half8 per thread (pre-split)
    {
      *(half8v*)&Bh[kcT][app][0] = *(const half8v*)&v16_w2hi[app*576 + kt + kcT*8];
      *(half8v*)&Bl[kcT][app][0] = *(const half8v*)&v16_w2lo[app*576 + kt + kcT*8];
    }
    __syncthreads();
    int row = wv*16 + fr;
    half8v ah = *(const half8v*)&Ah[fg][row][0];
    half8v al = *(const half8v*)&Al[fg][row][0];
    #pragma unroll
    for (int nf=0;nf<4;nf++){
      int col = nf*16 + fr;
      half8v bh = *(const half8v*)&Bh[fg][col][0];
      half8v bl = *(const half8v*)&Bl[fg][col][0];
      acc[nf] = __builtin_amdgcn_mfma_f32_16x16x32_f16(ah, bh, acc[nf], 0,0,0);
      acc[nf] = __builtin_amdgcn_mfma_f32_16x16x32_f16(ah, bl, acc[nf], 0,0,0);
      acc[nf] = __builtin_amdgcn_mfma_f32_16x16x32_f16(al, bh, acc[nf], 0,0,0);
    }
  }
  // BN + ReLU -> sfeat; C layout col=lane&15, row=(lane>>4)*4+j
  #pragma unroll
  for (int nf=0;nf<4;nf++){
    int ch = nf*16 + fr;
    float sc = g2[ch]/sqrtf(v2[ch]+1e-5f);
    float sh = b2_[ch] - m2[ch]*sc;
    float bi = eb[ch];
    #pragma unroll
    for (int j=0;j<4;j++){
      int pp = wv*16 + fg*4 + j;
      float t = (acc[nf][j] + bi)*sc + sh;
      sfeat[pp*68 + ch] = t > 0.f ? t : 0.f;
    }
  }
  __syncthreads();
  // head: 7x64, partial over 16 channels per og, LDS reduce
  int og = tid >> 6, pix = tid & 63;
  float part[7];
  #pragma unroll
  for (int o=0;o<7;o++) part[o]=0.f;
  #pragma unroll
  for (int j=0;j<16;j++){
    int oc = og*16 + j;
    float v = sfeat[pix*68 + oc];
    #pragma unroll
    for (int o=0;o<7;o++) part[o] += hw[o*64+oc]*v;
  }
  #pragma unroll
  for (int o=0;o<7;o++) hred[(og*64+pix)*7+o] = part[o];
  __syncthreads();
  if (og == 0){
    int gy = by*8 + (pix>>3), gx = bx*8 + (pix&7);
    #pragma unroll
    for (int o=0;o<7;o++){
      float s = hred[pix*7+o] + hred[(64+pix)*7+o] + hred[(128+pix)*7+o]
              + hred[(192+pix)*7+o] + hb[o];
      out0[o*16384 + gy*128 + gx] = s;
    }
  }
}

extern "C" void kernel_launch(void* const* d_in, const int* in_sizes, int n_in,
                              void* d_out, int out_size, void* d_ws, size_t ws_size,
                              hipStream_t stream){
  const float* imgs       = (const float*)d_in[0];
  const float* rots       = (const float*)d_in[1];
  const float* trans      = (const float*)d_in[2];
  const float* intrins    = (const float*)d_in[3];
  const float* post_rots  = (const float*)d_in[4];
  const float* post_trans = (const float*)d_in[5];
  const float* conv_w     = (const float*)d_in[6];
  const float* conv_b     = (const float*)d_in[7];
  const float* bn1_g      = (const float*)d_in[8];
  const float* bn1_b      = (const float*)d_in[9];
  const float* bn1_m      = (const float*)d_in[10];
  const float* bn1_v      = (const float*)d_in[11];
  const float* depth_w    = (const float*)d_in[12];
  const float* depth_b    = (const float*)d_in[13];
  const float* enc_w      = (const float*)d_in[14];
  const float* enc_b      = (const float*)d_in[15];
  const float* bn2_g      = (const float*)d_in[16];
  const float* bn2_b      = (const float*)d_in[17];
  const float* bn2_m      = (const float*)d_in[18];
  const float* bn2_v      = (const float*)d_in[19];
  const float* head_w     = (const float*)d_in[20];
  const float* head_b     = (const float*)d_in[21];

  float* out0 = (float*)d_out;          // (1,7,128,128)
  float* out1 = out0 + 114688;          // (1,64,128,128)

  prep_v22<<<5121, 256, 0, stream>>>(conv_w, depth_w, enc_w,
                                     rots, trans, intrins, post_rots, post_trans);
  conv1_v22<<<1056, 256, 0, stream>>>(imgs, conv_b, bn1_g, bn1_b, bn1_m, bn1_v);
  depth_v16<<<264, 256, 0, stream>>>(depth_b);
  rank_v13<<<(NPTS+1023)/1024, 256, 0, stream>>>();
  scan_v13<<<1, 256, 0, stream>>>();
  fill_v13<<<NPTS/256, 256, 0, stream>>>();
  gather_v13<<<NPTS/256, 256, 0, stream>>>();
  bevout_v11<<<4096, 256, 0, stream>>>(out1);
  conv2_v17<<<256, 256, 0, stream>>>(enc_b, bn2_g, bn2_b, bn2_m, bn2_v,
                                     head_w, head_b, out0);
}

// Round 14
// 258.154 us; speedup vs baseline: 1.0789x; 1.0431x over previous
//
#include <hip/hip_runtime.h>
#include <hip/hip_bf16.h>
#include <hip/hip_fp16.h>

#define NPTS 692736      // 24*41*16*44
#define NPATCH 16896     // 24*16*44

typedef _Float16 h16;
typedef __attribute__((ext_vector_type(4))) _Float16 half4v;
typedef __attribute__((ext_vector_type(8))) _Float16 half8v;
typedef __attribute__((ext_vector_type(4))) float f32x4;

// ---------- module-scope device globals ----------
__device__ float  v11_xbuf[NPATCH*256];
__device__ float  v11_ctx[NPATCH*64];
__device__ float  v11_depth[NPATCH*41];
__device__ int    v11_ranks[NPTS];
__device__ float  v11_bev[16384*64];
__device__ double v11_geom[24*24];

// conv1 weights pre-packed in LDS-tile order: [ob(4)][kt(12)][kc(8)][o(64)][8]
__device__ h16    v20_whi[196608];
__device__ h16    v20_wlo[196608];

// f16 hi/lo split depth weights, padded [112][256] ([o][c])
__device__ h16    v15_dwhi[112*256];
__device__ h16    v15_dwlo[112*256];

// f16 hi/lo split folded conv2 weights, [o][k] with k = tap*64 + ic
__device__ h16    v16_w2hi[64*576];
__device__ h16    v16_w2lo[64*576];

// counting-sort state for scatter->gather inversion
__device__ int    v12_cnt[16384];
__device__ int    v12_off[16384];
__device__ int    v12_pos[NPTS];       // position within own voxel
__device__ int2   v12_sorted[NPTS];    // (packed (p<<6)|d, rank) in rank order
__device__ int    v12_total;

__device__ __forceinline__ void inv3_v11(const double* m, double* o){
  double a=m[0],b=m[1],c=m[2],d=m[3],e=m[4],f=m[5],g=m[6],h=m[7],i=m[8];
  double A = e*i - f*h, B = -(d*i - f*g), C = d*h - e*g;
  double det = a*A + b*B + c*C;
  double id = 1.0/det;
  o[0]=A*id;            o[1]=-(b*i - c*h)*id; o[2]=(b*f - c*e)*id;
  o[3]=B*id;            o[4]=(a*i - c*g)*id;  o[5]=-(a*f - c*d)*id;
  o[6]=C*id;            o[7]=-(a*h - b*g)*id; o[8]=(a*e - b*d)*id;
}

// fused prep: bev/cnt zero + conv1 weight pack + depth/conv2 weight splits + geom
// grid = 4096 (zero) + 768 (wt) + 112 (wtd) + 144 (w2) + 1 (geom) = 5121 blocks
__global__ void prep_v20(const float* cw, const float* dw, const float* enc_w,
                         const float* rots, const float* trans, const float* intrins,
                         const float* post_rots, const float* post_trans){
  int b = blockIdx.x;
  int tid = threadIdx.x;
  if (b < 4096){
    int gid = b*256 + tid;
    v11_bev[gid] = 0.f;
    if (gid < 16384) v12_cnt[gid] = 0;
  } else if (b < 4864){
    // pack conv_w into [ob(4)][kt(12)][kc(8)][o(64)][8] + f16 hi/lo split
    int gid = (b-4096)*256 + tid;        // 0..196607
    int e  = gid & 7;
    int t  = gid >> 3;
    int o  = t & 63;
    int t2 = t >> 6;
    int kc = t2 & 7;
    int t3 = t2 >> 3;        // 0..47
    int kt = t3 % 12;
    int ob = t3 / 12;
    int k  = kt*64 + kc*8 + e;
    int oc = ob*64 + o;
    float x = cw[oc*768 + k];
    h16 hi = (h16)x;
    v20_whi[gid] = hi;
    v20_wlo[gid] = (h16)(x - (float)hi);
  } else if (b < 4976){
    // split depth_w [105][256] -> padded [112][256]
    int gid = (b-4864)*256 + tid;        // 0..28671
    int o = gid >> 8, c = gid & 255;
    float x = (o < 105) ? dw[o*256 + c] : 0.f;
    h16 hi = (h16)x;
    v15_dwhi[gid] = hi;
    v15_dwlo[gid] = (h16)(x - (float)hi);
  } else if (b < 5120){
    // fold enc_w concat halves, k-order = tap*64+ic
    int gid = (b-4976)*256 + tid;
    if (gid < 36864){
      int o = gid / 576; int k = gid % 576;
      int tap = k >> 6, ic = k & 63;
      float x = enc_w[o*1152 + ic*9 + tap] + enc_w[o*1152 + (ic+64)*9 + tap];
      h16 hi = (h16)x;
      v16_w2hi[gid] = hi;
      v16_w2lo[gid] = (h16)(x - (float)hi);
    }
  } else {
    // geom
    int t = tid;
    if (t >= 24) return;
    double pr[9], it[9], r[9];
    for (int i=0;i<9;i++){
      pr[i] = (double)post_rots[t*9+i];
      it[i] = (double)intrins[t*9+i];
      r[i]  = (double)rots[t*9+i];
    }
    double ipr[9], iit[9];
    inv3_v11(pr, ipr); inv3_v11(it, iit);
    double* g = v11_geom + t*24;
    for (int i=0;i<3;i++) for(int j=0;j<3;j++){
      double s=0; for(int k=0;k<3;k++) s += r[i*3+k]*iit[k*3+j];
      g[9+i*3+j]=s;
    }
    for (int i=0;i<9;i++) g[i]   = ipr[i];
    for (int i=0;i<3;i++) g[18+i]= (double)post_trans[t*3+i];
    for (int i=0;i<3;i++) g[21+i]= (double)trans[t*3+i];
  }
}

// conv1 as f16-split MFMA GEMM: C[16896x256] = A[16896x768] * W[768x256]
// v20: block tile 64(M) x 64(N) x 64(K), 4 waves (2Mx2N), wave sub-tile 32x32.
// 1056 blocks (~4/CU), LDS 32 KB. Register double-buffer retained.
__global__ __launch_bounds__(256) void conv1_v20(const float* img,
    const float* cb, const float* g1, const float* b1, const float* m1, const float* v1){
  __shared__ __align__(16) h16 Ah[8][64][8];    //  8 KB
  __shared__ __align__(16) h16 Al[8][64][8];    //  8 KB
  __shared__ __align__(16) h16 Bh[4096];        //  8 KB  ([kc][o][8] flat)
  __shared__ __align__(16) h16 Bl[4096];        //  8 KB
  int tid  = threadIdx.x;
  int lane = tid & 63, wv = tid >> 6;
  int wr = wv >> 1, wc = wv & 1;          // wave grid 2(M) x 2(N)
  int pbase = blockIdx.x * 64;

  // A tasks: (pp = tid>>3, kc = tid&7); two rows pp0, pp0+32
  int pp0 = tid >> 3, kc0 = tid & 7;
  const float* ab[2];
  #pragma unroll
  for (int i=0;i<2;i++){
    int p = pbase + pp0 + 32*i;
    int im = p/704, pix = p%704;
    int ph = pix/44, pw = pix%44;
    ab[i] = img + (size_t)im*540672 + (size_t)ph*16*704 + pw*16;
  }
  const h16* wph = v20_whi + (size_t)blockIdx.y*12*4096;
  const h16* wpl = v20_wlo + (size_t)blockIdx.y*12*4096;

  // prefetch registers
  float4 pa0[2], pa1[2];
  half8v pbh[2], pbl[2];

  auto LOAD_A = [&](int ktI){
    int k0 = ktI*64 + kc0*8;
    int c = k0>>8, rem = k0&255, ky = rem>>4, kx = rem&15;
    size_t goff = (size_t)c*180224 + ky*704 + kx;
    #pragma unroll
    for (int i=0;i<2;i++){
      pa0[i] = *(const float4*)(ab[i] + goff);
      pa1[i] = *(const float4*)(ab[i] + goff + 4);
    }
  };
  auto LOAD_B = [&](int ktI){
    const h16* ph = wph + (size_t)ktI*4096;
    const h16* pl = wpl + (size_t)ktI*4096;
    #pragma unroll
    for (int i=0;i<2;i++){
      int l = tid + i*256;
      pbh[i] = *(const half8v*)(ph + l*8);
      pbl[i] = *(const half8v*)(pl + l*8);
    }
  };

  f32x4 acc[2][2];
  #pragma unroll
  for (int mf=0;mf<2;mf++)
    #pragma unroll
    for (int nf=0;nf<2;nf++) acc[mf][nf] = (f32x4){0.f,0.f,0.f,0.f};

  int fr = lane & 15, fg = lane >> 4;

  LOAD_A(0); LOAD_B(0);

  for (int ktI=0; ktI<12; ktI++){
    __syncthreads();
    // write phase: split prefetched A regs -> LDS (XOR row swizzle), B linear
    #pragma unroll
    for (int i=0;i<2;i++){
      float vv[8] = {pa0[i].x,pa0[i].y,pa0[i].z,pa0[i].w,
                     pa1[i].x,pa1[i].y,pa1[i].z,pa1[i].w};
      half8v hv, lv;
      #pragma unroll
      for (int e=0;e<8;e++){ h16 h=(h16)vv[e]; hv[e]=h; lv[e]=(h16)(vv[e]-(float)h); }
      int srow = (pp0 + 32*i) ^ kc0;
      *(half8v*)&Ah[kc0][srow][0] = hv;
      *(half8v*)&Al[kc0][srow][0] = lv;
    }
    #pragma unroll
    for (int i=0;i<2;i++){
      int l = tid + i*256;
      *(half8v*)&Bh[l*8] = pbh[i];
      *(half8v*)&Bl[l*8] = pbl[i];
    }
    __syncthreads();
    // issue next tile's loads (fly under MFMA)
    if (ktI < 11){ LOAD_A(ktI+1); LOAD_B(ktI+1); }
    #pragma unroll
    for (int ks=0;ks<2;ks++){
      int kc = ks*4 + fg;
      half8v ah[2], al[2], bh[2], bl[2];
      #pragma unroll
      for (int mf=0;mf<2;mf++){
        int row = (wr*32 + mf*16 + fr) ^ kc;
        ah[mf] = *(const half8v*)&Ah[kc][row][0];
        al[mf] = *(const half8v*)&Al[kc][row][0];
      }
      #pragma unroll
      for (int nf=0;nf<2;nf++){
        int col = wc*32 + nf*16 + fr;
        bh[nf] = *(const half8v*)&Bh[(kc*64 + col)*8];
        bl[nf] = *(const half8v*)&Bl[(kc*64 + col)*8];
      }
      #pragma unroll
      for (int mf=0;mf<2;mf++)
        #pragma unroll
        for (int nf=0;nf<2;nf++){
          acc[mf][nf] = __builtin_amdgcn_mfma_f32_16x16x32_f16(ah[mf], bh[nf], acc[mf][nf], 0,0,0);
          acc[mf][nf] = __builtin_amdgcn_mfma_f32_16x16x32_f16(ah[mf], bl[nf], acc[mf][nf], 0,0,0);
          acc[mf][nf] = __builtin_amdgcn_mfma_f32_16x16x32_f16(al[mf], bh[nf], acc[mf][nf], 0,0,0);
        }
    }
  }
  // epilogue: BN + ReLU, C layout col=lane&15, row=(lane>>4)*4+j
  int obase = blockIdx.y * 64;
  #pragma unroll
  for (int nf=0;nf<2;nf++){
    int ch = obase + wc*32 + nf*16 + fr;
    float sc = g1[ch] / sqrtf(v1[ch] + 1e-5f);
    float sh = b1[ch] - m1[ch]*sc;
    float bi = cb[ch];
    #pragma unroll
    for (int mf=0;mf<2;mf++){
      #pragma unroll
      for (int j=0;j<4;j++){
        int pq = pbase + wr*32 + mf*16 + fg*4 + j;
        float t = (acc[mf][nf][j] + bi)*sc + sh;
        v11_xbuf[(size_t)pq*256 + ch] = t > 0.f ? t : 0.f;
      }
    }
  }
}

// depth head as f16-split MFMA GEMM: y[16896x105] = x[16896x256] * W^T[256x105]
// block = 64 patches, N padded to 112, K=256, BK=32 with [kc][row][8] LDS layout.
__global__ __launch_bounds__(256) void depth_v16(const float* db){
  __shared__ __align__(16) h16 Ah[4][64][8];    // 4 KB
  __shared__ __align__(16) h16 Al[4][64][8];
  __shared__ __align__(16) h16 Bh[4][112][8];   // 7 KB
  __shared__ __align__(16) h16 Bl[4][112][8];
  __shared__ float sy[64*113];   // 28,928 B
  int tid = threadIdx.x;
  int lane = tid & 63, wv = tid >> 6;
  int pbase = blockIdx.x*64;
  int fr = lane & 15, fg = lane >> 4;

  int app = tid & 63;            // A task: row fixed, kc = tid>>6
  int kcA = tid >> 6;
  const float* xsrc = &v11_xbuf[(size_t)(pbase+app)*256 + kcA*8];

  f32x4 acc[7];
  #pragma unroll
  for (int nf=0;nf<7;nf++) acc[nf] = (f32x4){0.f,0.f,0.f,0.f};

  for (int kt=0; kt<256; kt+=32){
    __syncthreads();
    // stage A from fp32 xbuf with in-flight hi/lo split (one half8 row/thread)
    {
      float4 v0 = *(const float4*)(xsrc + kt);
      float4 v1 = *(const float4*)(xsrc + kt + 4);
      float vv[8] = {v0.x,v0.y,v0.z,v0.w,v1.x,v1.y,v1.z,v1.w};
      half8v hv, lv;
      #pragma unroll
      for (int e=0;e<8;e++){ h16 h=(h16)vv[e]; hv[e]=h; lv[e]=(h16)(vv[e]-(float)h); }
      *(half8v*)&Ah[kcA][app][0] = hv;
      *(half8v*)&Al[kcA][app][0] = lv;
    }
    // stage W (pre-split, padded rows zero): 448 tasks, kc = l/112, o = l%112
    for (int l = tid; l < 448; l += 256){
      int kc = l/112, o = l%112;
      *(half8v*)&Bh[kc][o][0] = *(const half8v*)&v15_dwhi[o*256 + kt + kc*8];
      *(half8v*)&Bl[kc][o][0] = *(const half8v*)&v15_dwlo[o*256 + kt + kc*8];
    }
    __syncthreads();
    int row = wv*16 + fr;
    half8v ah = *(const half8v*)&Ah[fg][row][0];
    half8v al = *(const half8v*)&Al[fg][row][0];
    #pragma unroll
    for (int nf=0;nf<7;nf++){
      int col = nf*16 + fr;
      half8v bh = *(const half8v*)&Bh[fg][col][0];
      half8v bl = *(const half8v*)&Bl[fg][col][0];
      acc[nf] = __builtin_amdgcn_mfma_f32_16x16x32_f16(ah, bh, acc[nf], 0,0,0);
      acc[nf] = __builtin_amdgcn_mfma_f32_16x16x32_f16(ah, bl, acc[nf], 0,0,0);
      acc[nf] = __builtin_amdgcn_mfma_f32_16x16x32_f16(al, bh, acc[nf], 0,0,0);
    }
  }
  // y -> LDS with bias; C layout col=lane&15, row=(lane>>4)*4+j
  #pragma unroll
  for (int nf=0;nf<7;nf++){
    int o = nf*16 + fr;
    if (o < 105){
      float bias = db[o];
      #pragma unroll
      for (int j=0;j<4;j++){
        int pp = wv*16 + fg*4 + j;
        sy[pp*113 + o] = acc[nf][j] + bias;
      }
    }
  }
  __syncthreads();
  // softmax over first 41 per patch (64 threads, one per patch)
  if (tid < 64){
    float* y = &sy[tid*113];
    float m = y[0];
    for (int i=1;i<41;i++) m = fmaxf(m, y[i]);
    float s = 0.f;
    for (int i=0;i<41;i++){ float e = expf(y[i]-m); y[i] = e; s += e; }
    float inv = 1.f/s;
    for (int i=0;i<41;i++) y[i] *= inv;
  }
  __syncthreads();
  // write depth + ctx (coalesced)
  for (int l = tid; l < 64*41; l += 256){
    int pp = l/41, dd = l%41;
    v11_depth[(size_t)(pbase+pp)*41 + dd] = sy[pp*113+dd];
  }
  for (int l = tid; l < 64*64; l += 256){
    int pp = l>>6, c = l&63;
    v11_ctx[(size_t)(pbase+pp)*64 + c] = sy[pp*113 + 41 + c];
  }
}

// voxel rank per point + skew-immune LDS histogram + per-point voxel position.
__global__ __launch_bounds__(256) void rank_v13(){
  __shared__ int lh[16384];
  int tid = threadIdx.x;
  for (int i = tid; i < 16384; i += 256) lh[i] = 0;
  __syncthreads();
  int base = blockIdx.x*1024;
  int rk[4], lp[4];
  #pragma unroll
  for (int k=0;k<4;k++){
    int idx = base + k*256 + tid;
    rk[k] = -1; lp[k] = 0;
    if (idx < NPTS){
      int im = idx / 28864;
      int r  = idx % 28864;
      int d  = r / 704; int pix = r % 704;
      int h = pix / 44, w = pix % 44;
      const double* g = v11_geom + im*24;
      double fx = (double)w * (703.0/43.0);
      double fy = (double)h * 17.0;
      double fz = 4.0 + (double)d;
      double px = fx - g[18], py = fy - g[19], pz = fz - g[20];
      double q0 = g[0]*px + g[1]*py + g[2]*pz;
      double q1 = g[3]*px + g[4]*py + g[5]*pz;
      double q2 = g[6]*px + g[7]*py + g[8]*pz;
      q0 *= q2; q1 *= q2;
      double o0 = g[9]*q0  + g[10]*q1 + g[11]*q2 + g[21];
      double o1 = g[12]*q0 + g[13]*q1 + g[14]*q2 + g[22];
      double o2 = g[15]*q0 + g[16]*q1 + g[17]*q2 + g[23];
      int cx = (int)((o0 + 51.2)/0.8);
      int cy = (int)((o1 + 51.2)/0.8);
      int cz = (int)((o2 + 10.0)/20.0);
      int rank = cx + cy*128 + cz*16384;
      if (rank >= 0 && rank < 16384){
        rk[k] = rank;
        lp[k] = atomicAdd(&lh[rank], 1);   // position within block's local count
      }
    }
  }
  __syncthreads();
  // flush nonzero bins; lh[bin] becomes this block's global base for that bin
  for (int i = tid; i < 16384; i += 256){
    int h = lh[i];
    if (h) lh[i] = atomicAdd(&v12_cnt[i], h);
  }
  __syncthreads();
  #pragma unroll
  for (int k=0;k<4;k++){
    int idx = base + k*256 + tid;
    if (idx < NPTS){
      v11_ranks[idx] = rk[k];
      if (rk[k] >= 0) v12_pos[idx] = lh[rk[k]] + lp[k];
    }
  }
}

// exclusive scan over 16384 counts -> offsets + total, single block
__global__ __launch_bounds__(256) void scan_v13(){
  __shared__ int part[256];
  int t = threadIdx.x;
  int base = t*64;
  int s = 0;
  for (int i=0;i<64;i++) s += v12_cnt[base+i];
  part[t] = s;
  __syncthreads();
  if (t == 0){
    int run = 0;
    for (int i=0;i<256;i++){ int v = part[i]; part[i] = run; run += v; }
    v12_total = run;
  }
  __syncthreads();
  int run = part[t];
  for (int i=0;i<64;i++){
    v12_off[base+i] = run;
    run += v12_cnt[base+i];
  }
}

// place points into rank-sorted order — NO atomics (position precomputed)
__global__ __launch_bounds__(256) void fill_v13(){
  int idx = blockIdx.x*256 + threadIdx.x;
  if (idx >= NPTS) return;
  int rank = v11_ranks[idx];
  if (rank < 0) return;
  int im = idx / 28864;
  int r  = idx % 28864;
  int d  = r / 704; int pix = r % 704;
  int p  = im*704 + pix;
  int pos = v12_off[rank] + v12_pos[idx];
  v12_sorted[pos] = make_int2((p<<6) | d, rank);
}

// work-balanced segmented reduction: one wave per 64 sorted points, lane = channel.
__global__ __launch_bounds__(256) void gather_v13(){
  int total = v12_total;
  int w = threadIdx.x >> 6;
  int chunk = blockIdx.x*256 + w*64;
  if (chunk >= total) return;
  int lane = threadIdx.x & 63;
  int n = total - chunk; if (n > 64) n = 64;
  // per-lane coalesced load of one point (packed, rank) + its depth weight
  int pv = 0, rv = -1;
  float dv = 0.f;
  if (lane < n){
    int2 sr = v12_sorted[chunk + lane];
    pv = sr.x; rv = sr.y;
    dv = v11_depth[(pv>>6)*41 + (pv & 63)];
  }
  float acc = 0.f;
  int cur = __shfl(rv, 0);
  for (int i = 0; i < n; i++){
    int rk = __shfl(rv, i);
    int pp = __shfl(pv, i) >> 6;
    float dd = __shfl(dv, i);
    if (rk != cur){                       // wave-uniform branch
      atomicAdd(&v11_bev[(size_t)cur*64 + lane], acc);
      acc = 0.f; cur = rk;
    }
    acc += v11_ctx[(pp<<6) | lane] * dd;  // coalesced 256B row read
  }
  atomicAdd(&v11_bev[(size_t)cur*64 + lane], acc);
}

// conv2 3x3 SAME as f16-split implicit-GEMM MFMA + BN2 + ReLU + 7x64 head.
// Block = 8x8 pixel tile (M=64) x N=64, K=576 (tap*64+ic), [kc][row][8] LDS layout.
// bevout folded: center-tap (tap==4) staging writes out1 = transpose(bev).
__global__ __launch_bounds__(256) void conv2_v20(
    const float* eb, const float* g2, const float* b2_, const float* m2, const float* v2,
    const float* hw, const float* hb, float* out0, float* out1){
  __shared__ __align__(16) h16 Ah[4][64][8];    // 4 KB
  __shared__ __align__(16) h16 Al[4][64][8];
  __shared__ __align__(16) h16 Bh[4][64][8];
  __shared__ __align__(16) h16 Bl[4][64][8];
  __shared__ float sfeat[64*68]; // 17,408 B
  __shared__ float hred[4*64*7]; //  7,168 B
  int tid = threadIdx.x;
  int lane = tid & 63, wv = tid >> 6;
  int bx = blockIdx.x & 15, by = blockIdx.x >> 4;
  int fr = lane & 15, fg = lane >> 4;

  int app = tid & 63;            // A/B task: row fixed, kc = tid>>6
  int kcT = tid >> 6;
  int apy = app >> 3, apx = app & 7;

  f32x4 acc[4];
  #pragma unroll
  for (int nf=0;nf<4;nf++) acc[nf] = (f32x4){0.f,0.f,0.f,0.f};

  for (int kt=0; kt<576; kt+=32){
    int tap = kt >> 6, ic0 = kt & 32;
    int dy = tap/3 - 1, dx = tap%3 - 1;
    __syncthreads();
    // stage A: one half8 (8 channels) per thread from bev (boundary-zero)
    {
      int gy = by*8 + apy + dy, gx = bx*8 + apx + dx;
      float4 v0 = {0.f,0.f,0.f,0.f}, v1 = {0.f,0.f,0.f,0.f};
      if (gy>=0 && gy<128 && gx>=0 && gx<128){
        const float* src = &v11_bev[(size_t)(gy*128+gx)*64 + ic0 + kcT*8];
        v0 = *(const float4*)src;
        v1 = *(const float4*)(src+4);
      }
      float vv[8] = {v0.x,v0.y,v0.z,v0.w,v1.x,v1.y,v1.z,v1.w};
      // folded bevout: center tap passes each (pixel, channel) exactly once
      if (tap == 4){
        int gyc = by*8 + apy, gxc = bx*8 + apx;
        int ch0 = ic0 + kcT*8;
        #pragma unroll
        for (int q=0;q<8;q++)
          out1[(ch0+q)*16384 + gyc*128 + gxc] = vv[q];
      }
      half8v hv, lv;
      #pragma unroll
      for (int e=0;e<8;e++){ h16 h=(h16)vv[e]; hv[e]=h; lv[e]=(h16)(vv[e]-(float)h); }
      *(half8v*)&Ah[kcT][app][0] = hv;
      *(half8v*)&Al[kcT][app][0] = lv;
    }
    // stage W: one half8 per thread (pre-split)
    {
      *(half8v*)&Bh[kcT][app][0] = *(const half8v*)&v16_w2hi[app*576 + kt + kcT*8];
      *(half8v*)&Bl[kcT][app][0] = *(const half8v*)&v16_w2lo[app*576 + kt + kcT*8];
    }
    __syncthreads();
    int row = wv*16 + fr;
    half8v ah = *(const half8v*)&Ah[fg][row][0];
    half8v al = *(const half8v*)&Al[fg][row][0];
    #pragma unroll
    for (int nf=0;nf<4;nf++){
      int col = nf*16 + fr;
      half8v bh = *(const half8v*)&Bh[fg][col][0];
      half8v bl = *(const half8v*)&Bl[fg][col][0];
      acc[nf] = __builtin_amdgcn_mfma_f32_16x16x32_f16(ah, bh, acc[nf], 0,0,0);
      acc[nf] = __builtin_amdgcn_mfma_f32_16x16x32_f16(ah, bl, acc[nf], 0,0,0);
      acc[nf] = __builtin_amdgcn_mfma_f32_16x16x32_f16(al, bh, acc[nf], 0,0,0);
    }
  }
  // BN + ReLU -> sfeat; C layout col=lane&15, row=(lane>>4)*4+j
  #pragma unroll
  for (int nf=0;nf<4;nf++){
    int ch = nf*16 + fr;
    float sc = g2[ch]/sqrtf(v2[ch]+1e-5f);
    float sh = b2_[ch] - m2[ch]*sc;
    float bi = eb[ch];
    #pragma unroll
    for (int j=0;j<4;j++){
      int pp = wv*16 + fg*4 + j;
      float t = (acc[nf][j] + bi)*sc + sh;
      sfeat[pp*68 + ch] = t > 0.f ? t : 0.f;
    }
  }
  __syncthreads();
  // head: 7x64, partial over 16 channels per og, LDS reduce
  int og = tid >> 6, pix = tid & 63;
  float part[7];
  #pragma unroll
  for (int o=0;o<7;o++) part[o]=0.f;
  #pragma unroll
  for (int j=0;j<16;j++){
    int oc = og*16 + j;
    float v = sfeat[pix*68 + oc];
    #pragma unroll
    for (int o=0;o<7;o++) part[o] += hw[o*64+oc]*v;
  }
  #pragma unroll
  for (int o=0;o<7;o++) hred[(og*64+pix)*7+o] = part[o];
  __syncthreads();
  if (og == 0){
    int gy = by*8 + (pix>>3), gx = bx*8 + (pix&7);
    #pragma unroll
    for (int o=0;o<7;o++){
      float s = hred[pix*7+o] + hred[(64+pix)*7+o] + hred[(128+pix)*7+o]
              + hred[(192+pix)*7+o] + hb[o];
      out0[o*16384 + gy*128 + gx] = s;
    }
  }
}

extern "C" void kernel_launch(void* const* d_in, const int* in_sizes, int n_in,
                              void* d_out, int out_size, void* d_ws, size_t ws_size,
                              hipStream_t stream){
  const float* imgs       = (const float*)d_in[0];
  const float* rots       = (const float*)d_in[1];
  const float* trans      = (const float*)d_in[2];
  const float* intrins    = (const float*)d_in[3];
  const float* post_rots  = (const float*)d_in[4];
  const float* post_trans = (const float*)d_in[5];
  const float* conv_w     = (const float*)d_in[6];
  const float* conv_b     = (const float*)d_in[7];
  const float* bn1_g      = (const float*)d_in[8];
  const float* bn1_b      = (const float*)d_in[9];
  const float* bn1_m      = (const float*)d_in[10];
  const float* bn1_v      = (const float*)d_in[11];
  const float* depth_w    = (const float*)d_in[12];
  const float* depth_b    = (const float*)d_in[13];
  const float* enc_w      = (const float*)d_in[14];
  const float* enc_b      = (const float*)d_in[15];
  const float* bn2_g      = (const float*)d_in[16];
  const float* bn2_b      = (const float*)d_in[17];
  const float* bn2_m      = (const float*)d_in[18];
  const float* bn2_v      = (const float*)d_in[19];
  const float* head_w     = (const float*)d_in[20];
  const float* head_b     = (const float*)d_in[21];

  float* out0 = (float*)d_out;          // (1,7,128,128)
  float* out1 = out0 + 114688;          // (1,64,128,128)

  prep_v20<<<5121, 256, 0, stream>>>(conv_w, depth_w, enc_w,
                                     rots, trans, intrins, post_rots, post_trans);
  conv1_v20<<<dim3(264, 4), 256, 0, stream>>>(imgs, conv_b, bn1_g, bn1_b, bn1_m, bn1_v);
  depth_v16<<<264, 256, 0, stream>>>(depth_b);
  rank_v13<<<(NPTS+1023)/1024, 256, 0, stream>>>();
  scan_v13<<<1, 256, 0, stream>>>();
  fill_v13<<<NPTS/256, 256, 0, stream>>>();
  gather_v13<<<NPTS/256, 256, 0, stream>>>();
  conv2_v20<<<256, 256, 0, stream>>>(enc_b, bn2_g, bn2_b, bn2_m, bn2_v,
                                     head_w, head_b, out0, out1);
}